// Round 4
// baseline (18455.273 us; speedup 1.0000x reference)
//
#include <hip/hip_runtime.h>
#include <hip/hip_bf16.h>

#define E 2048
#define T_STEPS 512

// ---------------- prep kernels ----------------

// W_outT[e][d] = W_out[d][e]   (128 x 2048 -> 2048 x 128), for k_out coalescing
__global__ void k_transpose_wout(const float* __restrict__ wout, float* __restrict__ woutT) {
    int o = blockIdx.x * blockDim.x + threadIdx.x;
    if (o >= E * 128) return;
    int e = o >> 7, d = o & 127;
    woutT[o] = wout[d * E + e];
}

// bias0 = b_ih0 + b_hh0 ; bias1 = b_ih1 + b_hh1
__global__ void k_bias(const float* __restrict__ bih0, const float* __restrict__ bhh0,
                       const float* __restrict__ bih1, const float* __restrict__ bhh1,
                       float* __restrict__ bias0, float* __restrict__ bias1) {
    int r = blockIdx.x * blockDim.x + threadIdx.x;
    if (r >= 4 * E) return;
    bias0[r] = bih0[r] + bhh0[r];
    bias1[r] = bih1[r] + bhh1[r];
}

// hist[0] = lat, h0buf[0] = lat, c0 = c1 = 0
__global__ void k_init(const float* __restrict__ lat, float* __restrict__ hist0,
                       float* __restrict__ h0buf0, float* __restrict__ c0,
                       float* __restrict__ c1) {
    int i = blockIdx.x * blockDim.x + threadIdx.x;
    if (i >= E) return;
    float v = lat[i];
    hist0[i] = v;
    h0buf0[i] = v;
    c0[i] = 0.f;
    c1[i] = 0.f;
}

// ---------------- per-step kernels ----------------

// x[d] = b_out[d] + dot(W_out[d][:], h)   -- 128 blocks x 64 lanes
__global__ __launch_bounds__(64) void k_x(const float* __restrict__ wout,
                                          const float* __restrict__ h,
                                          const float* __restrict__ bout,
                                          float* __restrict__ x) {
    const int d = blockIdx.x;
    const int l = threadIdx.x;
    const float* w = wout + (size_t)d * E;
    float acc = 0.f;
#pragma unroll
    for (int v = 0; v < 8; ++v) {
        int idx = v * 256 + l * 4;
        float4 u = *(const float4*)(w + idx);
        float4 r = *(const float4*)(h + idx);
        acc = fmaf(u.x, r.x, acc);
        acc = fmaf(u.y, r.y, acc);
        acc = fmaf(u.z, r.z, acc);
        acc = fmaf(u.w, r.w, acc);
    }
#pragma unroll
    for (int off = 32; off > 0; off >>= 1) acc += __shfl_xor(acc, off);
    if (l == 0) x[d] = acc + bout[d];
}

// layer 0: gates = W_ih0 @ x (row len 128) + W_hh0 @ h0in (row len 2048) + bias
__global__ __launch_bounds__(64) void k_l0(
    const float* __restrict__ Wih0, const float* __restrict__ x,
    const float* __restrict__ Whh0, const float* __restrict__ h0in,
    const float* __restrict__ bias, float* __restrict__ c, float* __restrict__ hout) {
    const int e = blockIdx.x;
    const int l = threadIdx.x;

    // preload h0in into registers: 8 float4 per lane
    float4 rh[8];
#pragma unroll
    for (int v = 0; v < 8; ++v) rh[v] = *(const float4*)(h0in + v * 256 + l * 4);
    // preload x (128 floats): 2 per lane
    float2 rx = *(const float2*)(x + l * 2);

    float g[4];
#pragma unroll
    for (int q = 0; q < 4; ++q) {
        const float* wi = Wih0 + (size_t)(q * E + e) * 128;
        const float* wh = Whh0 + (size_t)(q * E + e) * E;
        float2 wix = *(const float2*)(wi + l * 2);
        float acc = fmaf(wix.x, rx.x, wix.y * rx.y);
#pragma unroll
        for (int v = 0; v < 8; ++v) {
            float4 u = *(const float4*)(wh + v * 256 + l * 4);
            float4 r = rh[v];
            acc = fmaf(u.x, r.x, acc);
            acc = fmaf(u.y, r.y, acc);
            acc = fmaf(u.z, r.z, acc);
            acc = fmaf(u.w, r.w, acc);
        }
#pragma unroll
        for (int off = 32; off > 0; off >>= 1) acc += __shfl_xor(acc, off);
        g[q] = acc;
    }

    if (l == 0) {
        float gi = g[0] + bias[e];
        float gf = g[1] + bias[E + e];
        float gg = g[2] + bias[2 * E + e];
        float go = g[3] + bias[3 * E + e];
        float i = 1.f / (1.f + expf(-gi));
        float f = 1.f / (1.f + expf(-gf));
        float gv = tanhf(gg);
        float o = 1.f / (1.f + expf(-go));
        float cn = fmaf(f, c[e], i * gv);
        c[e] = cn;
        hout[e] = o * tanhf(cn);
    }
}

// layer 1: gates = Wa @ ina + Wb @ inb + bias  (both rows len 2048)
__global__ __launch_bounds__(64) void k_l1(
    const float* __restrict__ Wa, const float* __restrict__ ina,
    const float* __restrict__ Wb, const float* __restrict__ inb,
    const float* __restrict__ bias, float* __restrict__ c, float* __restrict__ hout) {
    const int e = blockIdx.x;
    const int l = threadIdx.x;

    float4 ra[8], rb[8];
#pragma unroll
    for (int v = 0; v < 8; ++v) {
        int idx = v * 256 + l * 4;
        ra[v] = *(const float4*)(ina + idx);
        rb[v] = *(const float4*)(inb + idx);
    }

    float g[4];
#pragma unroll
    for (int q = 0; q < 4; ++q) {
        const float* wa = Wa + (size_t)(q * E + e) * E;
        const float* wb = Wb + (size_t)(q * E + e) * E;
        float acc = 0.f;
#pragma unroll
        for (int v = 0; v < 8; ++v) {
            int idx = v * 256 + l * 4;
            float4 u = *(const float4*)(wa + idx);
            float4 r = ra[v];
            acc = fmaf(u.x, r.x, acc);
            acc = fmaf(u.y, r.y, acc);
            acc = fmaf(u.z, r.z, acc);
            acc = fmaf(u.w, r.w, acc);
            float4 w = *(const float4*)(wb + idx);
            float4 s = rb[v];
            acc = fmaf(w.x, s.x, acc);
            acc = fmaf(w.y, s.y, acc);
            acc = fmaf(w.z, s.z, acc);
            acc = fmaf(w.w, s.w, acc);
        }
#pragma unroll
        for (int off = 32; off > 0; off >>= 1) acc += __shfl_xor(acc, off);
        g[q] = acc;
    }

    if (l == 0) {
        float gi = g[0] + bias[e];
        float gf = g[1] + bias[E + e];
        float gg = g[2] + bias[2 * E + e];
        float go = g[3] + bias[3 * E + e];
        float i = 1.f / (1.f + expf(-gi));
        float f = 1.f / (1.f + expf(-gf));
        float gv = tanhf(gg);
        float o = 1.f / (1.f + expf(-go));
        float cn = fmaf(f, c[e], i * gv);
        c[e] = cn;
        hout[e] = o * tanhf(cn);
    }
}

// ---------------- final output GEMM ----------------
// out[t][d] = b_out[d] + sum_e W_outT[e][d] * hist[t][e]   (fp32 store)
__global__ __launch_bounds__(128) void k_out(const float* __restrict__ woutT,
                                             const float* __restrict__ hist,
                                             const float* __restrict__ bout,
                                             float* __restrict__ out) {
    __shared__ float h[E];
    int t = blockIdx.x, d = threadIdx.x;
    for (int i = d; i < E; i += 128) h[i] = hist[(size_t)t * E + i];
    __syncthreads();
    float acc0 = bout[d], acc1 = 0.f;
#pragma unroll 4
    for (int k = 0; k < E; k += 2) {
        acc0 = fmaf(woutT[k * 128 + d], h[k], acc0);
        acc1 = fmaf(woutT[(k + 1) * 128 + d], h[k + 1], acc1);
    }
    out[t * 128 + d] = acc0 + acc1;
}

extern "C" void kernel_launch(void* const* d_in, const int* in_sizes, int n_in,
                              void* d_out, int out_size, void* d_ws, size_t ws_size,
                              hipStream_t stream) {
    const float* lat = (const float*)d_in[0];
    const float* wih0 = (const float*)d_in[1];
    const float* whh0 = (const float*)d_in[2];
    const float* bih0 = (const float*)d_in[3];
    const float* bhh0 = (const float*)d_in[4];
    const float* wih1 = (const float*)d_in[5];
    const float* whh1 = (const float*)d_in[6];
    const float* bih1 = (const float*)d_in[7];
    const float* bhh1 = (const float*)d_in[8];
    const float* wout = (const float*)d_in[9];
    const float* bout = (const float*)d_in[10];

    char* p = (char*)d_ws;
    float* woutT = (float*)p; p += (size_t)E * 128 * 4;
    float* bias0 = (float*)p; p += (size_t)4 * E * 4;
    float* bias1 = (float*)p; p += (size_t)4 * E * 4;
    float* hist = (float*)p;  p += (size_t)T_STEPS * E * 4;
    float* h0buf = (float*)p; p += (size_t)2 * E * 4;
    float* c0 = (float*)p;    p += (size_t)E * 4;
    float* c1 = (float*)p;    p += (size_t)E * 4;
    float* xbuf = (float*)p;  p += (size_t)128 * 4;

    k_transpose_wout<<<(E * 128 + 255) / 256, 256, 0, stream>>>(wout, woutT);
    k_bias<<<(4 * E + 255) / 256, 256, 0, stream>>>(bih0, bhh0, bih1, bhh1, bias0, bias1);
    k_init<<<(E + 255) / 256, 256, 0, stream>>>(lat, hist, h0buf, c0, c1);

    for (int s = 1; s < T_STEPS; ++s) {
        // x(s) = W_out @ h1(s-1) + b_out   (hist[0] = lat)
        k_x<<<128, 64, 0, stream>>>(wout, hist + (size_t)(s - 1) * E, bout, xbuf);
        // layer 0: gates0 = W_ih0 @ x + W_hh0 @ h0(s-1) + bias0
        k_l0<<<E, 64, 0, stream>>>(wih0, xbuf, whh0,
                                   h0buf + (size_t)((s - 1) & 1) * E, bias0, c0,
                                   h0buf + (size_t)(s & 1) * E);
        // layer 1: gates1 = W_ih1 @ h0(s) + W_hh1 @ h1(s-1) + bias1
        k_l1<<<E, 64, 0, stream>>>(wih1, h0buf + (size_t)(s & 1) * E, whh1,
                                   hist + (size_t)(s - 1) * E, bias1, c1,
                                   hist + (size_t)s * E);
    }

    k_out<<<T_STEPS, 128, 0, stream>>>(woutT, hist, bout, (float*)d_out);
}

// Round 5
// 11462.041 us; speedup vs baseline: 1.6101x; 1.6101x over previous
//
#include <hip/hip_runtime.h>
#include <hip/hip_fp16.h>

typedef unsigned short u16;
typedef unsigned int u32;

#define E 2048
#define T_STEPS 512

// ---------------- fp16 helpers ----------------
__device__ __forceinline__ u32 packh2(float a, float b) {
    return (u32)__half_as_ushort(__float2half_rn(a)) |
           ((u32)__half_as_ushort(__float2half_rn(b)) << 16);
}
__device__ __forceinline__ float hlo(u32 u) {
    return __half2float(__ushort_as_half((u16)(u & 0xffffu)));
}
__device__ __forceinline__ float hhi(u32 u) {
    return __half2float(__ushort_as_half((u16)(u >> 16)));
}

// ---------------- prep kernels ----------------

// fp32 -> fp16 packed; n8 = n/8
__global__ __launch_bounds__(256) void k_cvt_f16(const float* __restrict__ in,
                                                 u16* __restrict__ out, int n8) {
    int i = blockIdx.x * blockDim.x + threadIdx.x;
    if (i >= n8) return;
    const float4* p = (const float4*)in + (size_t)i * 2;
    float4 a = p[0], b = p[1];
    uint4 r;
    r.x = packh2(a.x, a.y);
    r.y = packh2(a.z, a.w);
    r.z = packh2(b.x, b.y);
    r.w = packh2(b.z, b.w);
    ((uint4*)out)[i] = r;
}

// W_outT[e][d] = W_out[d][e]   (fp32, for k_out coalescing)
__global__ void k_transpose_wout(const float* __restrict__ wout, float* __restrict__ woutT) {
    int o = blockIdx.x * blockDim.x + threadIdx.x;
    if (o >= E * 128) return;
    int e = o >> 7, d = o & 127;
    woutT[o] = wout[d * E + e];
}

// bias0 = b_ih0 + b_hh0 ; bias1 = b_ih1 + b_hh1
__global__ void k_bias(const float* __restrict__ bih0, const float* __restrict__ bhh0,
                       const float* __restrict__ bih1, const float* __restrict__ bhh1,
                       float* __restrict__ bias0, float* __restrict__ bias1) {
    int r = blockIdx.x * blockDim.x + threadIdx.x;
    if (r >= 4 * E) return;
    bias0[r] = bih0[r] + bhh0[r];
    bias1[r] = bih1[r] + bhh1[r];
}

// hist[0] = lat, h0buf[0] = lat, c0 = c1 = 0
__global__ void k_init(const float* __restrict__ lat, float* __restrict__ hist0,
                       float* __restrict__ h0buf0, float* __restrict__ c0,
                       float* __restrict__ c1) {
    int i = blockIdx.x * blockDim.x + threadIdx.x;
    if (i >= E) return;
    float v = lat[i];
    hist0[i] = v;
    h0buf0[i] = v;
    c0[i] = 0.f;
    c1[i] = 0.f;
}

// ---------------- LSTM epilogue (shared) ----------------
__device__ __forceinline__ void lstm_epilogue(int e, const float g[4],
                                              const float* __restrict__ bias,
                                              float* __restrict__ c,
                                              float* __restrict__ hout) {
    float gi = g[0] + bias[e];
    float gf = g[1] + bias[E + e];
    float gg = g[2] + bias[2 * E + e];
    float go = g[3] + bias[3 * E + e];
    float i = 1.f / (1.f + expf(-gi));
    float f = 1.f / (1.f + expf(-gf));
    float gv = tanhf(gg);
    float o = 1.f / (1.f + expf(-go));
    float cn = fmaf(f, c[e], i * gv);
    c[e] = cn;
    hout[e] = o * tanhf(cn);
}

// ---------------- fp16-weight step kernels ----------------

// x[d] = b_out[d] + dot(W_out[d][:], h)
__global__ __launch_bounds__(64) void k_xh(const u16* __restrict__ wout,
                                           const float* __restrict__ h,
                                           const float* __restrict__ bout,
                                           float* __restrict__ x) {
    const int d = blockIdx.x;
    const int l = threadIdx.x;
    const u16* w = wout + (size_t)d * E;
    float acc = 0.f;
#pragma unroll
    for (int v = 0; v < 4; ++v) {
        int idx = v * 512 + l * 8;
        uint4 u = *(const uint4*)(w + idx);
        float4 r0 = *(const float4*)(h + idx);
        float4 r1 = *(const float4*)(h + idx + 4);
        acc = fmaf(hlo(u.x), r0.x, acc);
        acc = fmaf(hhi(u.x), r0.y, acc);
        acc = fmaf(hlo(u.y), r0.z, acc);
        acc = fmaf(hhi(u.y), r0.w, acc);
        acc = fmaf(hlo(u.z), r1.x, acc);
        acc = fmaf(hhi(u.z), r1.y, acc);
        acc = fmaf(hlo(u.w), r1.z, acc);
        acc = fmaf(hhi(u.w), r1.w, acc);
    }
#pragma unroll
    for (int off = 32; off > 0; off >>= 1) acc += __shfl_xor(acc, off);
    if (l == 0) x[d] = acc + bout[d];
}

// layer 0: gates = W_ih0 @ x (128) + W_hh0 @ h0in (2048) + bias
__global__ __launch_bounds__(64) void k_l0h(
    const u16* __restrict__ Wih0, const float* __restrict__ x,
    const u16* __restrict__ Whh0, const float* __restrict__ h0in,
    const float* __restrict__ bias, float* __restrict__ c, float* __restrict__ hout) {
    const int e = blockIdx.x;
    const int l = threadIdx.x;

    float4 rh[8];
#pragma unroll
    for (int v = 0; v < 4; ++v) {
        int idx = v * 512 + l * 8;
        rh[v * 2] = *(const float4*)(h0in + idx);
        rh[v * 2 + 1] = *(const float4*)(h0in + idx + 4);
    }
    float2 rx = *(const float2*)(x + l * 2);

    float g[4];
#pragma unroll
    for (int q = 0; q < 4; ++q) {
        const u16* wi = Wih0 + (size_t)(q * E + e) * 128;
        const u16* wh = Whh0 + (size_t)(q * E + e) * E;
        u32 wix = *(const u32*)(wi + l * 2);
        float acc = fmaf(hlo(wix), rx.x, hhi(wix) * rx.y);
#pragma unroll
        for (int v = 0; v < 4; ++v) {
            int idx = v * 512 + l * 8;
            uint4 u = *(const uint4*)(wh + idx);
            float4 r0 = rh[v * 2], r1 = rh[v * 2 + 1];
            acc = fmaf(hlo(u.x), r0.x, acc);
            acc = fmaf(hhi(u.x), r0.y, acc);
            acc = fmaf(hlo(u.y), r0.z, acc);
            acc = fmaf(hhi(u.y), r0.w, acc);
            acc = fmaf(hlo(u.z), r1.x, acc);
            acc = fmaf(hhi(u.z), r1.y, acc);
            acc = fmaf(hlo(u.w), r1.z, acc);
            acc = fmaf(hhi(u.w), r1.w, acc);
        }
#pragma unroll
        for (int off = 32; off > 0; off >>= 1) acc += __shfl_xor(acc, off);
        g[q] = acc;
    }

    if (l == 0) lstm_epilogue(e, g, bias, c, hout);
}

// layer 1: gates = Wa @ ina + Wb @ inb + bias (both 2048)
__global__ __launch_bounds__(64) void k_l1h(
    const u16* __restrict__ Wa, const float* __restrict__ ina,
    const u16* __restrict__ Wb, const float* __restrict__ inb,
    const float* __restrict__ bias, float* __restrict__ c, float* __restrict__ hout) {
    const int e = blockIdx.x;
    const int l = threadIdx.x;

    float4 ra[8], rb[8];
#pragma unroll
    for (int v = 0; v < 4; ++v) {
        int idx = v * 512 + l * 8;
        ra[v * 2] = *(const float4*)(ina + idx);
        ra[v * 2 + 1] = *(const float4*)(ina + idx + 4);
        rb[v * 2] = *(const float4*)(inb + idx);
        rb[v * 2 + 1] = *(const float4*)(inb + idx + 4);
    }

    float g[4];
#pragma unroll
    for (int q = 0; q < 4; ++q) {
        const u16* wa = Wa + (size_t)(q * E + e) * E;
        const u16* wb = Wb + (size_t)(q * E + e) * E;
        float acca = 0.f, accb = 0.f;
#pragma unroll
        for (int v = 0; v < 4; ++v) {
            int idx = v * 512 + l * 8;
            uint4 ua = *(const uint4*)(wa + idx);
            uint4 ub = *(const uint4*)(wb + idx);
            float4 r0 = ra[v * 2], r1 = ra[v * 2 + 1];
            acca = fmaf(hlo(ua.x), r0.x, acca);
            acca = fmaf(hhi(ua.x), r0.y, acca);
            acca = fmaf(hlo(ua.y), r0.z, acca);
            acca = fmaf(hhi(ua.y), r0.w, acca);
            acca = fmaf(hlo(ua.z), r1.x, acca);
            acca = fmaf(hhi(ua.z), r1.y, acca);
            acca = fmaf(hlo(ua.w), r1.z, acca);
            acca = fmaf(hhi(ua.w), r1.w, acca);
            float4 s0 = rb[v * 2], s1 = rb[v * 2 + 1];
            accb = fmaf(hlo(ub.x), s0.x, accb);
            accb = fmaf(hhi(ub.x), s0.y, accb);
            accb = fmaf(hlo(ub.y), s0.z, accb);
            accb = fmaf(hhi(ub.y), s0.w, accb);
            accb = fmaf(hlo(ub.z), s1.x, accb);
            accb = fmaf(hhi(ub.z), s1.y, accb);
            accb = fmaf(hlo(ub.w), s1.z, accb);
            accb = fmaf(hhi(ub.w), s1.w, accb);
        }
        float t = acca + accb;
#pragma unroll
        for (int off = 32; off > 0; off >>= 1) t += __shfl_xor(t, off);
        g[q] = t;
    }

    if (l == 0) lstm_epilogue(e, g, bias, c, hout);
}

// ---------------- fp32 fallback step kernels ----------------

__global__ __launch_bounds__(64) void k_x(const float* __restrict__ wout,
                                          const float* __restrict__ h,
                                          const float* __restrict__ bout,
                                          float* __restrict__ x) {
    const int d = blockIdx.x;
    const int l = threadIdx.x;
    const float* w = wout + (size_t)d * E;
    float acc = 0.f;
#pragma unroll
    for (int v = 0; v < 8; ++v) {
        int idx = v * 256 + l * 4;
        float4 u = *(const float4*)(w + idx);
        float4 r = *(const float4*)(h + idx);
        acc = fmaf(u.x, r.x, acc);
        acc = fmaf(u.y, r.y, acc);
        acc = fmaf(u.z, r.z, acc);
        acc = fmaf(u.w, r.w, acc);
    }
#pragma unroll
    for (int off = 32; off > 0; off >>= 1) acc += __shfl_xor(acc, off);
    if (l == 0) x[d] = acc + bout[d];
}

__global__ __launch_bounds__(64) void k_l0(
    const float* __restrict__ Wih0, const float* __restrict__ x,
    const float* __restrict__ Whh0, const float* __restrict__ h0in,
    const float* __restrict__ bias, float* __restrict__ c, float* __restrict__ hout) {
    const int e = blockIdx.x;
    const int l = threadIdx.x;
    float4 rh[8];
#pragma unroll
    for (int v = 0; v < 8; ++v) rh[v] = *(const float4*)(h0in + v * 256 + l * 4);
    float2 rx = *(const float2*)(x + l * 2);
    float g[4];
#pragma unroll
    for (int q = 0; q < 4; ++q) {
        const float* wi = Wih0 + (size_t)(q * E + e) * 128;
        const float* wh = Whh0 + (size_t)(q * E + e) * E;
        float2 wix = *(const float2*)(wi + l * 2);
        float acc = fmaf(wix.x, rx.x, wix.y * rx.y);
#pragma unroll
        for (int v = 0; v < 8; ++v) {
            float4 u = *(const float4*)(wh + v * 256 + l * 4);
            float4 r = rh[v];
            acc = fmaf(u.x, r.x, acc);
            acc = fmaf(u.y, r.y, acc);
            acc = fmaf(u.z, r.z, acc);
            acc = fmaf(u.w, r.w, acc);
        }
#pragma unroll
        for (int off = 32; off > 0; off >>= 1) acc += __shfl_xor(acc, off);
        g[q] = acc;
    }
    if (l == 0) lstm_epilogue(e, g, bias, c, hout);
}

__global__ __launch_bounds__(64) void k_l1(
    const float* __restrict__ Wa, const float* __restrict__ ina,
    const float* __restrict__ Wb, const float* __restrict__ inb,
    const float* __restrict__ bias, float* __restrict__ c, float* __restrict__ hout) {
    const int e = blockIdx.x;
    const int l = threadIdx.x;
    float4 ra[8], rb[8];
#pragma unroll
    for (int v = 0; v < 8; ++v) {
        int idx = v * 256 + l * 4;
        ra[v] = *(const float4*)(ina + idx);
        rb[v] = *(const float4*)(inb + idx);
    }
    float g[4];
#pragma unroll
    for (int q = 0; q < 4; ++q) {
        const float* wa = Wa + (size_t)(q * E + e) * E;
        const float* wb = Wb + (size_t)(q * E + e) * E;
        float acc = 0.f;
#pragma unroll
        for (int v = 0; v < 8; ++v) {
            int idx = v * 256 + l * 4;
            float4 u = *(const float4*)(wa + idx);
            float4 r = ra[v];
            acc = fmaf(u.x, r.x, acc);
            acc = fmaf(u.y, r.y, acc);
            acc = fmaf(u.z, r.z, acc);
            acc = fmaf(u.w, r.w, acc);
            float4 w = *(const float4*)(wb + idx);
            float4 s = rb[v];
            acc = fmaf(w.x, s.x, acc);
            acc = fmaf(w.y, s.y, acc);
            acc = fmaf(w.z, s.z, acc);
            acc = fmaf(w.w, s.w, acc);
        }
#pragma unroll
        for (int off = 32; off > 0; off >>= 1) acc += __shfl_xor(acc, off);
        g[q] = acc;
    }
    if (l == 0) lstm_epilogue(e, g, bias, c, hout);
}

// ---------------- final output GEMM ----------------
__global__ __launch_bounds__(128) void k_out(const float* __restrict__ woutT,
                                             const float* __restrict__ hist,
                                             const float* __restrict__ bout,
                                             float* __restrict__ out) {
    __shared__ float h[E];
    int t = blockIdx.x, d = threadIdx.x;
    for (int i = d; i < E; i += 128) h[i] = hist[(size_t)t * E + i];
    __syncthreads();
    float acc0 = bout[d], acc1 = 0.f;
#pragma unroll 4
    for (int k = 0; k < E; k += 2) {
        acc0 = fmaf(woutT[k * 128 + d], h[k], acc0);
        acc1 = fmaf(woutT[(k + 1) * 128 + d], h[k + 1], acc1);
    }
    out[t * 128 + d] = acc0 + acc1;
}

extern "C" void kernel_launch(void* const* d_in, const int* in_sizes, int n_in,
                              void* d_out, int out_size, void* d_ws, size_t ws_size,
                              hipStream_t stream) {
    const float* lat = (const float*)d_in[0];
    const float* wih0 = (const float*)d_in[1];
    const float* whh0 = (const float*)d_in[2];
    const float* bih0 = (const float*)d_in[3];
    const float* bhh0 = (const float*)d_in[4];
    const float* wih1 = (const float*)d_in[5];
    const float* whh1 = (const float*)d_in[6];
    const float* bih1 = (const float*)d_in[7];
    const float* bhh1 = (const float*)d_in[8];
    const float* wout = (const float*)d_in[9];
    const float* bout = (const float*)d_in[10];

    const size_t WB = (size_t)4 * E * E * sizeof(u16);  // 33.55 MB
    const size_t need_f16 = 3 * WB + (size_t)4 * E * 128 * 2 + (size_t)128 * E * 2 +
                            (size_t)E * 128 * 4 + 2 * (size_t)4 * E * 4 +
                            (size_t)T_STEPS * E * 4 + (size_t)4 * E * 4 + 4096;

    char* p = (char*)d_ws;
    u16* Whh0h = nullptr; u16* Wih1h = nullptr; u16* Whh1h = nullptr;
    u16* Wih0h = nullptr; u16* Wouth = nullptr;
    const bool f16 = ws_size >= need_f16;
    if (f16) {
        Whh0h = (u16*)p; p += WB;
        Wih1h = (u16*)p; p += WB;
        Whh1h = (u16*)p; p += WB;
        Wih0h = (u16*)p; p += (size_t)4 * E * 128 * 2;
        Wouth = (u16*)p; p += (size_t)128 * E * 2;
    }
    float* woutT = (float*)p; p += (size_t)E * 128 * 4;
    float* bias0 = (float*)p; p += (size_t)4 * E * 4;
    float* bias1 = (float*)p; p += (size_t)4 * E * 4;
    float* hist = (float*)p;  p += (size_t)T_STEPS * E * 4;
    float* h0buf = (float*)p; p += (size_t)2 * E * 4;
    float* c0 = (float*)p;    p += (size_t)E * 4;
    float* c1 = (float*)p;    p += (size_t)E * 4;
    float* xbuf = (float*)p;  p += (size_t)128 * 4;

    if (f16) {
        const int n8 = 4 * E * E / 8;
        k_cvt_f16<<<(n8 + 255) / 256, 256, 0, stream>>>(whh0, Whh0h, n8);
        k_cvt_f16<<<(n8 + 255) / 256, 256, 0, stream>>>(wih1, Wih1h, n8);
        k_cvt_f16<<<(n8 + 255) / 256, 256, 0, stream>>>(whh1, Whh1h, n8);
        const int n8i = 4 * E * 128 / 8;
        k_cvt_f16<<<(n8i + 255) / 256, 256, 0, stream>>>(wih0, Wih0h, n8i);
        const int n8o = 128 * E / 8;
        k_cvt_f16<<<(n8o + 255) / 256, 256, 0, stream>>>(wout, Wouth, n8o);
    }
    k_transpose_wout<<<(E * 128 + 255) / 256, 256, 0, stream>>>(wout, woutT);
    k_bias<<<(4 * E + 255) / 256, 256, 0, stream>>>(bih0, bhh0, bih1, bhh1, bias0, bias1);
    k_init<<<(E + 255) / 256, 256, 0, stream>>>(lat, hist, h0buf, c0, c1);

    for (int s = 1; s < T_STEPS; ++s) {
        const float* h1p = hist + (size_t)(s - 1) * E;
        const float* h0p = h0buf + (size_t)((s - 1) & 1) * E;
        float* h0n = h0buf + (size_t)(s & 1) * E;
        float* h1n = hist + (size_t)s * E;
        if (f16) {
            k_xh<<<128, 64, 0, stream>>>(Wouth, h1p, bout, xbuf);
            k_l0h<<<E, 64, 0, stream>>>(Wih0h, xbuf, Whh0h, h0p, bias0, c0, h0n);
            k_l1h<<<E, 64, 0, stream>>>(Wih1h, h0n, Whh1h, h1p, bias1, c1, h1n);
        } else {
            k_x<<<128, 64, 0, stream>>>(wout, h1p, bout, xbuf);
            k_l0<<<E, 64, 0, stream>>>(wih0, xbuf, whh0, h0p, bias0, c0, h0n);
            k_l1<<<E, 64, 0, stream>>>(wih1, h0n, whh1, h1p, bias1, c1, h1n);
        }
    }

    k_out<<<T_STEPS, 128, 0, stream>>>(woutT, hist, bout, (float*)d_out);
}

// Round 6
// 9510.554 us; speedup vs baseline: 1.9405x; 1.2052x over previous
//
#include <hip/hip_runtime.h>
#include <hip/hip_fp16.h>

typedef unsigned short u16;
typedef unsigned int u32;
typedef signed char i8;

#define E 2048
#define T_STEPS 512

// ---------------- helpers ----------------
__device__ __forceinline__ u32 packh2(float a, float b) {
    return (u32)__half_as_ushort(__float2half_rn(a)) |
           ((u32)__half_as_ushort(__float2half_rn(b)) << 16);
}
__device__ __forceinline__ float hlo(u32 u) {
    return __half2float(__ushort_as_half((u16)(u & 0xffffu)));
}
__device__ __forceinline__ float hhi(u32 u) {
    return __half2float(__ushort_as_half((u16)(u >> 16)));
}
__device__ __forceinline__ float4 i8x4_to_f4(u32 v) {
    return make_float4((float)(i8)(v & 0xff), (float)(i8)((v >> 8) & 0xff),
                       (float)(i8)((v >> 16) & 0xff), (float)(i8)((v >> 24) & 0xff));
}
__device__ __forceinline__ float dot4(float4 a, float4 b, float acc) {
    acc = fmaf(a.x, b.x, acc);
    acc = fmaf(a.y, b.y, acc);
    acc = fmaf(a.z, b.z, acc);
    acc = fmaf(a.w, b.w, acc);
    return acc;
}

// ---------------- prep kernels ----------------

// fp32 -> fp16 packed; n8 = n/8
__global__ __launch_bounds__(256) void k_cvt_f16(const float* __restrict__ in,
                                                 u16* __restrict__ out, int n8) {
    int i = blockIdx.x * blockDim.x + threadIdx.x;
    if (i >= n8) return;
    const float4* p = (const float4*)in + (size_t)i * 2;
    float4 a = p[0], b = p[1];
    uint4 r;
    r.x = packh2(a.x, a.y);
    r.y = packh2(a.z, a.w);
    r.z = packh2(b.x, b.y);
    r.w = packh2(b.z, b.w);
    ((uint4*)out)[i] = r;
}

// per-row int8 quantization of a (4E x E) matrix: one wave per row
__global__ __launch_bounds__(64) void k_quant(const float* __restrict__ in,
                                              i8* __restrict__ q,
                                              float* __restrict__ scales) {
    const int r = blockIdx.x;
    const int l = threadIdx.x;
    const float* row = in + (size_t)r * E;
    float4 v[8];
    float m = 0.f;
#pragma unroll
    for (int u = 0; u < 8; ++u) {
        v[u] = *(const float4*)(row + u * 256 + l * 4);
        m = fmaxf(m, fmaxf(fmaxf(fabsf(v[u].x), fabsf(v[u].y)),
                           fmaxf(fabsf(v[u].z), fabsf(v[u].w))));
    }
#pragma unroll
    for (int off = 32; off > 0; off >>= 1) m = fmaxf(m, __shfl_xor(m, off));
    const float scale = fmaxf(m, 1e-30f) / 127.f;
    const float inv = 127.f / fmaxf(m, 1e-30f);
    i8* qr = q + (size_t)r * E;
#pragma unroll
    for (int u = 0; u < 8; ++u) {
        int a0 = (int)rintf(v[u].x * inv);
        int a1 = (int)rintf(v[u].y * inv);
        int a2 = (int)rintf(v[u].z * inv);
        int a3 = (int)rintf(v[u].w * inv);
        u32 pk = ((u32)(a0 & 0xff)) | ((u32)(a1 & 0xff) << 8) |
                 ((u32)(a2 & 0xff) << 16) | ((u32)(a3 & 0xff) << 24);
        *(u32*)(qr + u * 256 + l * 4) = pk;
    }
    if (l == 0) scales[r] = scale;
}

// W_outT[e][d] = W_out[d][e]   (fp32, for k_out coalescing)
__global__ void k_transpose_wout(const float* __restrict__ wout, float* __restrict__ woutT) {
    int o = blockIdx.x * blockDim.x + threadIdx.x;
    if (o >= E * 128) return;
    int e = o >> 7, d = o & 127;
    woutT[o] = wout[d * E + e];
}

// bias0 = b_ih0 + b_hh0 ; bias1 = b_ih1 + b_hh1
__global__ void k_bias(const float* __restrict__ bih0, const float* __restrict__ bhh0,
                       const float* __restrict__ bih1, const float* __restrict__ bhh1,
                       float* __restrict__ bias0, float* __restrict__ bias1) {
    int r = blockIdx.x * blockDim.x + threadIdx.x;
    if (r >= 4 * E) return;
    bias0[r] = bih0[r] + bhh0[r];
    bias1[r] = bih1[r] + bhh1[r];
}

// hist[0] = lat, h0buf[0] = lat, c0 = c1 = 0
__global__ void k_init(const float* __restrict__ lat, float* __restrict__ hist0,
                       float* __restrict__ h0buf0, float* __restrict__ c0,
                       float* __restrict__ c1) {
    int i = blockIdx.x * blockDim.x + threadIdx.x;
    if (i >= E) return;
    float v = lat[i];
    hist0[i] = v;
    h0buf0[i] = v;
    c0[i] = 0.f;
    c1[i] = 0.f;
}

// ---------------- LSTM epilogue (shared) ----------------
__device__ __forceinline__ void lstm_epilogue(int e, const float g[4],
                                              const float* __restrict__ bias,
                                              float* __restrict__ c,
                                              float* __restrict__ hout) {
    float gi = g[0] + bias[e];
    float gf = g[1] + bias[E + e];
    float gg = g[2] + bias[2 * E + e];
    float go = g[3] + bias[3 * E + e];
    float i = 1.f / (1.f + expf(-gi));
    float f = 1.f / (1.f + expf(-gf));
    float gv = tanhf(gg);
    float o = 1.f / (1.f + expf(-go));
    float cn = fmaf(f, c[e], i * gv);
    c[e] = cn;
    hout[e] = o * tanhf(cn);
}

// ---------------- per-step kernels ----------------

// x[d] = b_out[d] + dot(W_out[d][:], h)   (W_out fp16)
__global__ __launch_bounds__(64) void k_xh(const u16* __restrict__ wout,
                                           const float* __restrict__ h,
                                           const float* __restrict__ bout,
                                           float* __restrict__ x) {
    const int d = blockIdx.x;
    const int l = threadIdx.x;
    const u16* w = wout + (size_t)d * E;
    float acc = 0.f;
#pragma unroll
    for (int v = 0; v < 4; ++v) {
        int idx = v * 512 + l * 8;
        uint4 u = *(const uint4*)(w + idx);
        float4 r0 = *(const float4*)(h + idx);
        float4 r1 = *(const float4*)(h + idx + 4);
        acc = fmaf(hlo(u.x), r0.x, acc);
        acc = fmaf(hhi(u.x), r0.y, acc);
        acc = fmaf(hlo(u.y), r0.z, acc);
        acc = fmaf(hhi(u.y), r0.w, acc);
        acc = fmaf(hlo(u.z), r1.x, acc);
        acc = fmaf(hhi(u.z), r1.y, acc);
        acc = fmaf(hlo(u.w), r1.z, acc);
        acc = fmaf(hhi(u.w), r1.w, acc);
    }
#pragma unroll
    for (int off = 32; off > 0; off >>= 1) acc += __shfl_xor(acc, off);
    if (l == 0) x[d] = acc + bout[d];
}

// layer 0: gates = W_ih0 @ x (fp16, 128) + Q_hh0 @ h0in (int8, 2048) + bias
__global__ __launch_bounds__(64) void k_l0q(
    const u16* __restrict__ Wih0, const float* __restrict__ x,
    const i8* __restrict__ Qhh0, const float* __restrict__ sHH0,
    const float* __restrict__ h0in,
    const float* __restrict__ bias, float* __restrict__ c, float* __restrict__ hout) {
    const int e = blockIdx.x;
    const int l = threadIdx.x;

    // preload h0in: lane l covers elems u*1024 + l*16 .. +15  (8 float4)
    float4 rh[8];
#pragma unroll
    for (int u = 0; u < 2; ++u) {
        int base = u * 1024 + l * 16;
#pragma unroll
        for (int j = 0; j < 4; ++j) rh[u * 4 + j] = *(const float4*)(h0in + base + j * 4);
    }
    float2 rx = *(const float2*)(x + l * 2);

    float g[4];
#pragma unroll
    for (int q = 0; q < 4; ++q) {
        const int row = q * E + e;
        const u16* wi = Wih0 + (size_t)row * 128;
        const i8* wh = Qhh0 + (size_t)row * E;
        u32 wix = *(const u32*)(wi + l * 2);
        float acci = fmaf(hlo(wix), rx.x, hhi(wix) * rx.y);
        float acch = 0.f;
#pragma unroll
        for (int u = 0; u < 2; ++u) {
            uint4 ua = *(const uint4*)(wh + u * 1024 + l * 16);
            acch = dot4(i8x4_to_f4(ua.x), rh[u * 4 + 0], acch);
            acch = dot4(i8x4_to_f4(ua.y), rh[u * 4 + 1], acch);
            acch = dot4(i8x4_to_f4(ua.z), rh[u * 4 + 2], acch);
            acch = dot4(i8x4_to_f4(ua.w), rh[u * 4 + 3], acch);
        }
        float t = fmaf(acch, sHH0[row], acci);
#pragma unroll
        for (int off = 32; off > 0; off >>= 1) t += __shfl_xor(t, off);
        g[q] = t;
    }

    if (l == 0) lstm_epilogue(e, g, bias, c, hout);
}

// layer 1: gates = Qa @ ina + Qb @ inb + bias  (both int8, 2048)
__global__ __launch_bounds__(64) void k_l1q(
    const i8* __restrict__ Qa, const float* __restrict__ sA,
    const float* __restrict__ ina,
    const i8* __restrict__ Qb, const float* __restrict__ sB,
    const float* __restrict__ inb,
    const float* __restrict__ bias, float* __restrict__ c, float* __restrict__ hout) {
    const int e = blockIdx.x;
    const int l = threadIdx.x;

    float4 ra[8], rb[8];
#pragma unroll
    for (int u = 0; u < 2; ++u) {
        int base = u * 1024 + l * 16;
#pragma unroll
        for (int j = 0; j < 4; ++j) {
            ra[u * 4 + j] = *(const float4*)(ina + base + j * 4);
            rb[u * 4 + j] = *(const float4*)(inb + base + j * 4);
        }
    }

    float g[4];
#pragma unroll
    for (int q = 0; q < 4; ++q) {
        const int row = q * E + e;
        const i8* wa = Qa + (size_t)row * E;
        const i8* wb = Qb + (size_t)row * E;
        float acca = 0.f, accb = 0.f;
#pragma unroll
        for (int u = 0; u < 2; ++u) {
            uint4 ua = *(const uint4*)(wa + u * 1024 + l * 16);
            uint4 ub = *(const uint4*)(wb + u * 1024 + l * 16);
            acca = dot4(i8x4_to_f4(ua.x), ra[u * 4 + 0], acca);
            acca = dot4(i8x4_to_f4(ua.y), ra[u * 4 + 1], acca);
            acca = dot4(i8x4_to_f4(ua.z), ra[u * 4 + 2], acca);
            acca = dot4(i8x4_to_f4(ua.w), ra[u * 4 + 3], acca);
            accb = dot4(i8x4_to_f4(ub.x), rb[u * 4 + 0], accb);
            accb = dot4(i8x4_to_f4(ub.y), rb[u * 4 + 1], accb);
            accb = dot4(i8x4_to_f4(ub.z), rb[u * 4 + 2], accb);
            accb = dot4(i8x4_to_f4(ub.w), rb[u * 4 + 3], accb);
        }
        float t = acca * sA[row] + accb * sB[row];
#pragma unroll
        for (int off = 32; off > 0; off >>= 1) t += __shfl_xor(t, off);
        g[q] = t;
    }

    if (l == 0) lstm_epilogue(e, g, bias, c, hout);
}

// ---------------- final output GEMM ----------------
__global__ __launch_bounds__(128) void k_out(const float* __restrict__ woutT,
                                             const float* __restrict__ hist,
                                             const float* __restrict__ bout,
                                             float* __restrict__ out) {
    __shared__ float h[E];
    int t = blockIdx.x, d = threadIdx.x;
    for (int i = d; i < E; i += 128) h[i] = hist[(size_t)t * E + i];
    __syncthreads();
    float acc0 = bout[d], acc1 = 0.f;
#pragma unroll 4
    for (int k = 0; k < E; k += 2) {
        acc0 = fmaf(woutT[k * 128 + d], h[k], acc0);
        acc1 = fmaf(woutT[(k + 1) * 128 + d], h[k + 1], acc1);
    }
    out[t * 128 + d] = acc0 + acc1;
}

extern "C" void kernel_launch(void* const* d_in, const int* in_sizes, int n_in,
                              void* d_out, int out_size, void* d_ws, size_t ws_size,
                              hipStream_t stream) {
    const float* lat = (const float*)d_in[0];
    const float* wih0 = (const float*)d_in[1];
    const float* whh0 = (const float*)d_in[2];
    const float* bih0 = (const float*)d_in[3];
    const float* bhh0 = (const float*)d_in[4];
    const float* wih1 = (const float*)d_in[5];
    const float* whh1 = (const float*)d_in[6];
    const float* bih1 = (const float*)d_in[7];
    const float* bhh1 = (const float*)d_in[8];
    const float* wout = (const float*)d_in[9];
    const float* bout = (const float*)d_in[10];

    const size_t QB = (size_t)4 * E * E;  // 16.78 MB per int8 matrix
    char* p = (char*)d_ws;
    i8* Qhh0 = (i8*)p;  p += QB;
    i8* Qih1 = (i8*)p;  p += QB;
    i8* Qhh1 = (i8*)p;  p += QB;
    float* sHH0 = (float*)p; p += (size_t)4 * E * 4;
    float* sIH1 = (float*)p; p += (size_t)4 * E * 4;
    float* sHH1 = (float*)p; p += (size_t)4 * E * 4;
    u16* Wih0h = (u16*)p; p += (size_t)4 * E * 128 * 2;
    u16* Wouth = (u16*)p; p += (size_t)128 * E * 2;
    float* woutT = (float*)p; p += (size_t)E * 128 * 4;
    float* bias0 = (float*)p; p += (size_t)4 * E * 4;
    float* bias1 = (float*)p; p += (size_t)4 * E * 4;
    float* hist = (float*)p;  p += (size_t)T_STEPS * E * 4;
    float* h0buf = (float*)p; p += (size_t)2 * E * 4;
    float* c0 = (float*)p;    p += (size_t)E * 4;
    float* c1 = (float*)p;    p += (size_t)E * 4;
    float* xbuf = (float*)p;  p += (size_t)128 * 4;

    k_quant<<<4 * E, 64, 0, stream>>>(whh0, Qhh0, sHH0);
    k_quant<<<4 * E, 64, 0, stream>>>(wih1, Qih1, sIH1);
    k_quant<<<4 * E, 64, 0, stream>>>(whh1, Qhh1, sHH1);
    const int n8i = 4 * E * 128 / 8;
    k_cvt_f16<<<(n8i + 255) / 256, 256, 0, stream>>>(wih0, Wih0h, n8i);
    const int n8o = 128 * E / 8;
    k_cvt_f16<<<(n8o + 255) / 256, 256, 0, stream>>>(wout, Wouth, n8o);
    k_transpose_wout<<<(E * 128 + 255) / 256, 256, 0, stream>>>(wout, woutT);
    k_bias<<<(4 * E + 255) / 256, 256, 0, stream>>>(bih0, bhh0, bih1, bhh1, bias0, bias1);
    k_init<<<(E + 255) / 256, 256, 0, stream>>>(lat, hist, h0buf, c0, c1);

    for (int s = 1; s < T_STEPS; ++s) {
        const float* h1p = hist + (size_t)(s - 1) * E;
        const float* h0p = h0buf + (size_t)((s - 1) & 1) * E;
        float* h0n = h0buf + (size_t)(s & 1) * E;
        float* h1n = hist + (size_t)s * E;
        k_xh<<<128, 64, 0, stream>>>(Wouth, h1p, bout, xbuf);
        k_l0q<<<E, 64, 0, stream>>>(Wih0h, xbuf, Qhh0, sHH0, h0p, bias0, c0, h0n);
        k_l1q<<<E, 64, 0, stream>>>(Qih1, sIH1, h0n, Qhh1, sHH1, h1p, bias1, c1, h1n);
    }

    k_out<<<T_STEPS, 128, 0, stream>>>(woutT, hist, bout, (float*)d_out);
}